// Round 10
// baseline (2089.126 us; speedup 1.0000x reference)
//
#include <hip/hip_runtime.h>
#include <math.h>

#define HH 512
#define BB 64
#define SS 48
#define EE 512
#define G4 2048
#define EPSF 1e-5f
#define AGENT __HIP_MEMORY_SCOPE_AGENT

__device__ __forceinline__ float aload(const float* p) {
  return __hip_atomic_load(p, __ATOMIC_RELAXED, AGENT);   // sc1: MALL-coherent
}
__device__ __forceinline__ void astore(float* p, float v) {
  __hip_atomic_store(p, v, __ATOMIC_RELAXED, AGENT);
}

// ---- fast transcendentals (v_exp_f32 = 2^x, v_rcp_f32) ----
__device__ __forceinline__ float fsigmoid(float x) {
  float t = __builtin_amdgcn_exp2f(x * -1.44269504088896f);
  return __builtin_amdgcn_rcpf(1.f + t);
}
__device__ __forceinline__ float ftanh(float x) {
  x = fminf(fmaxf(x, -10.f), 10.f);
  float t = __builtin_amdgcn_exp2f(x * 2.88539008177793f);  // e^(2x)
  return (t - 1.f) * __builtin_amdgcn_rcpf(t + 1.f);
}

// counting barrier (preamble only)
__device__ __forceinline__ void gsync(int* c, int target) {
  __builtin_amdgcn_s_waitcnt(0);
  __syncthreads();
  if (threadIdx.x == 0) {
    __hip_atomic_fetch_add(c, 1, __ATOMIC_RELEASE, AGENT);
    int spins = 0;
    while (__hip_atomic_load(c, __ATOMIC_RELAXED, AGENT) < target) {
      __builtin_amdgcn_s_sleep(2);
      if (++spins > (1 << 21)) break;
    }
    (void)__hip_atomic_load(c, __ATOMIC_ACQUIRE, AGENT);
  }
  __syncthreads();
}

// 32-lane gather-min poll over 32 flag slots (128-B stride), proven pattern
__device__ __forceinline__ void flagpoll(const int* f, int t1, int tid) {
  if (tid < 32) {
    int spins = 0;
    for (;;) {
      int v = __hip_atomic_load(f + tid*32, __ATOMIC_RELAXED, AGENT);
      #pragma unroll
      for (int off = 16; off > 0; off >>= 1) v = min(v, __shfl_down(v, off, 32));
      v = __shfl(v, 0, 32);
      if (v >= t1) break;
      __builtin_amdgcn_s_sleep(1);
      if (++spins > (1 << 22)) break;
    }
  }
}

// ======== phase A: layer-0 input projection, full S, both dirs ========
__global__ __launch_bounds__(256)
void gemm_ih0(const float* __restrict__ x, const float* __restrict__ w_ih0,
              float* __restrict__ G0) {
  __shared__ float As[16][65];
  __shared__ float Bs[16][65];
  const int m0 = blockIdx.y * 64;
  const int d  = m0 / (BB * SS);
  const float* Wm = w_ih0 + (size_t)d * G4 * EE;
  const int bn = blockIdx.x * 64;
  const int tid = threadIdx.x;
  const int lrow = tid >> 2;
  const int lkk  = (tid & 3) << 2;
  const int tx = tid & 15;
  const int ty = tid >> 4;
  int m  = m0 + lrow;
  int r  = m - d * (BB * SS);
  int b  = r / SS;
  int tl = r - b * SS;
  int s  = d ? (SS - 1 - tl) : tl;
  const float* arow = x + ((size_t)b * SS + s) * EE;

  float acc[4][4] = {};
  for (int k0 = 0; k0 < EE; k0 += 16) {
    float4 av = *(const float4*)(arow + k0 + lkk);
    float4 bv = *(const float4*)(Wm + (size_t)(bn + lrow) * EE + k0 + lkk);
    As[lkk+0][lrow] = av.x; As[lkk+1][lrow] = av.y; As[lkk+2][lrow] = av.z; As[lkk+3][lrow] = av.w;
    Bs[lkk+0][lrow] = bv.x; Bs[lkk+1][lrow] = bv.y; Bs[lkk+2][lrow] = bv.z; Bs[lkk+3][lrow] = bv.w;
    __syncthreads();
    #pragma unroll
    for (int k = 0; k < 16; ++k) {
      float a[4], bbv[4];
      #pragma unroll
      for (int i = 0; i < 4; ++i) a[i] = As[k][ty*4+i];
      #pragma unroll
      for (int j = 0; j < 4; ++j) bbv[j] = Bs[k][tx*4+j];
      #pragma unroll
      for (int i = 0; i < 4; ++i)
        #pragma unroll
        for (int j = 0; j < 4; ++j) acc[i][j] += a[i]*bbv[j];
    }
    __syncthreads();
  }
  for (int i = 0; i < 4; ++i)
    for (int j = 0; j < 4; ++j)
      G0[(size_t)(m0 + ty*4 + i) * G4 + bn + tx*4 + j] = acc[i][j];
}

// ======== in-place LayerNorm on rows of 2048 ========
__global__ __launch_bounds__(256)
void ln_rows(float* __restrict__ X, const float* __restrict__ gamma,
             const float* __restrict__ beta, int rows_per_d) {
  __shared__ float red[8];
  const int row = blockIdx.x;
  const int d = row / rows_per_d;
  float* xr = X + (size_t)row * G4;
  const float* gg = gamma + (size_t)d * G4;
  const float* bb = beta  + (size_t)d * G4;
  float s = 0.f, q = 0.f;
  float v[8];
  #pragma unroll
  for (int it = 0; it < 8; ++it) {
    float xv = xr[threadIdx.x + it*256];
    v[it] = xv; s += xv; q += xv*xv;
  }
  #pragma unroll
  for (int off = 32; off > 0; off >>= 1) { s += __shfl_down(s, off); q += __shfl_down(q, off); }
  int lane = threadIdx.x & 63, wid = threadIdx.x >> 6;
  if (lane == 0) { red[wid] = s; red[4+wid] = q; }
  __syncthreads();
  float ts = red[0]+red[1]+red[2]+red[3];
  float tq = red[4]+red[5]+red[6]+red[7];
  float mu = ts * (1.f/G4);
  float rstd = rsqrtf(tq*(1.f/G4) - mu*mu + EPSF);
  #pragma unroll
  for (int it = 0; it < 8; ++it) {
    int jc = threadIdx.x + it*256;
    xr[jc] = (v[it]-mu)*rstd*gg[jc] + bb[jc];
  }
}

// ======== persistent scan: R4 protocol, two interleaved half-pipelines =====
// group g = bb&7 = (d, bq); jb = bb>>3 in [0,32). The group's 16 batch rows
// split into half0 (rows 0-7) and half1 (rows 8-15) with per-half flags and
// disjoint buffer rows. Phases interleave so every poll is preceded by the
// other half's compute:
//   GEMV0+pubR0+fA0 | GEMV1+pubR1+fA1 | pollA0,bcR0,upd0,fB0 |
//   pollA1,bcR1,upd1,fB1 | pollB0,bcC0,stage0 | pollB1,bcC1,stage1
// Sync primitives identical to the proven 1751us kernel (sc1 relaxed atomics,
// drain-via-__syncthreads before flag, gather-min poll, 128-B flag stride).
__global__ __launch_bounds__(1024, 4)
void persistP(const float* __restrict__ whh, const float* __restrict__ Gbuf,
              long g_row_stride, long g_t_stride,
              const float* __restrict__ lnhg, const float* __restrict__ lnhb,
              const float* __restrict__ lnog, const float* __restrict__ lnob,
              float* cbuf, float* obuf, float* Rpart, float* Cpart,
              int* flagsA, int* flagsB,
              float* fout, int nsteps,
              int mode1, const float* __restrict__ w_ih1,
              const float* __restrict__ xcb, float* g1pre,
              const float* __restrict__ ln_g1, const float* __restrict__ ln_b1,
              int* cnt_pre) {
  __shared__ float hlds[16][520];     // 33.3 KB
  __shared__ float part[16][8][64];   // 32 KB
  __shared__ float redR[16][64];      //  4 KB
  __shared__ float bcR[16][2];
  __shared__ float bcC[16][2];
  __shared__ float sred[32];

  const int bb = blockIdx.x;
  const int tid = threadIdx.x;

  // ---- mode1 preamble: layer-1 projection + LN(g1pre) ----
  if (mode1) {
    const int dp = bb & 1, nbp = bb >> 1;
    const int pb = tid >> 4, ns = tid & 15;
    const int col1 = nbp*16 + ns;
    const float* xrow = xcb + (size_t)pb * 1024;
    const float* wv_ = w_ih1 + ((size_t)dp*G4 + col1) * 1024;
    float a = 0.f;
    for (int k = 0; k < 1024; k += 4) {
      float4 xv = *(const float4*)(xrow + k);
      float4 wv4 = *(const float4*)(wv_ + k);
      a += xv.x*wv4.x + xv.y*wv4.y + xv.z*wv4.z + xv.w*wv4.w;
    }
    astore(g1pre + ((size_t)dp*BB + pb) * G4 + col1, a);
    gsync(cnt_pre + 0, 256);
    if (bb < 128) {
      const int ld = bb >> 6;
      float* xr = g1pre + (size_t)bb * G4;
      const float* gg = ln_g1 + (size_t)ld * G4;
      const float* be = ln_b1 + (size_t)ld * G4;
      float v0 = aload(xr + tid), v1 = aload(xr + tid + 1024);
      float s = v0 + v1, q = v0*v0 + v1*v1;
      #pragma unroll
      for (int off = 32; off > 0; off >>= 1) { s += __shfl_down(s, off); q += __shfl_down(q, off); }
      const int wv2 = tid >> 6;
      if ((tid & 63) == 0) { sred[wv2] = s; sred[16+wv2] = q; }
      __syncthreads();
      float ts = 0.f, tq = 0.f;
      #pragma unroll
      for (int i = 0; i < 16; ++i) { ts += sred[i]; tq += sred[16+i]; }
      float mu = ts * (1.f/G4);
      float rstd = rsqrtf(tq*(1.f/G4) - mu*mu + EPSF);
      astore(xr + tid,        (v0-mu)*rstd*gg[tid]      + be[tid]);
      astore(xr + tid + 1024, (v1-mu)*rstd*gg[tid+1024] + be[tid+1024]);
    }
    gsync(cnt_pre + 16, 256);
  }

  // ---- role decode ----
  const int g  = bb & 7;
  const int d  = g >> 2;
  const int bq = g & 3;
  const int jb = bb >> 3;
  const int rowbase = d*BB + bq*16;
  const int ke = tid >> 6, nl = tid & 63;       // GEMV: wave=k-slice, lane=col
  const int ncol = jb*16 + ((nl>>4) << 9) + (nl & 15);
  int* fA0 = flagsA + g*1024;                   // per-half flag regions
  int* fA1 = flagsA + 8192 + g*1024;
  int* fB0 = flagsB + g*1024;
  int* fB1 = flagsB + 8192 + g*1024;

  float wreg[32];
  {
    const float* wp = whh + ((size_t)d*G4 + ncol)*HH + (size_t)ke*32;
    #pragma unroll
    for (int i = 0; i < 32; ++i) wreg[i] = wp[i];
  }

  const int bl = tid >> 4;                      // update role (tid<128): row in half
  const int jl = tid & 15;
  const int jc = jb*16 + jl;
  const int scol = tid & 511, srh = tid >> 9;   // staging col, row-half
  const float ogv = lnog[(size_t)d*HH + scol];
  const float obv = lnob[(size_t)d*HH + scol];
  const int row8 = (tid >> 5) & 7, j32 = tid & 31;  // reduce roles (tid<256)
  const int inv_g = (g_t_stride == 0);
  const int rowcA = rowbase + bl;               // valid for tid<128
  const int rowcB = rowbase + 8 + bl;

  // ---- hoist step-invariant update params into registers ----
  float hg0=0,hg1=0,hg2=0,hg3=0, hb0=0,hb1=0,hb2=0,hb3=0;
  float cgA0=0,cgA1=0,cgA2=0,cgA3=0, cgB0=0,cgB1=0,cgB2=0,cgB3=0;
  if (tid < 128) {
    const float* lnhg_d = lnhg + (size_t)d*G4;
    const float* lnhb_d = lnhb + (size_t)d*G4;
    hg0 = lnhg_d[jc];        hb0 = lnhb_d[jc];
    hg1 = lnhg_d[HH+jc];     hb1 = lnhb_d[HH+jc];
    hg2 = lnhg_d[2*HH+jc];   hb2 = lnhb_d[2*HH+jc];
    hg3 = lnhg_d[3*HH+jc];   hb3 = lnhb_d[3*HH+jc];
    if (inv_g) {
      const float* ga = Gbuf + (size_t)rowcA * g_row_stride;
      const float* gb = Gbuf + (size_t)rowcB * g_row_stride;
      cgA0 = ga[jc]; cgA1 = ga[HH+jc]; cgA2 = ga[2*HH+jc]; cgA3 = ga[3*HH+jc];
      cgB0 = gb[jc]; cgB1 = gb[HH+jc]; cgB2 = gb[2*HH+jc]; cgB3 = gb[3*HH+jc];
    }
  }
  // ---- h(-1) = 0 ----
  {
    float* hz = &hlds[0][0];
    for (int u = tid; u < 16*520; u += 1024) hz[u] = 0.f;
  }
  __syncthreads();

  float cregA = 0.f, cregB = 0.f;

  for (int t = 0; t < nsteps; ++t) {
    // ======== GEMV half0 (rows 0-7) + reduce + Rpart publish + flagA0 ======
    #pragma unroll
    for (int b = 0; b < 8; ++b) {
      const float* hp = &hlds[b][ke*32];
      float acc = 0.f;
      #pragma unroll
      for (int i4 = 0; i4 < 8; ++i4) {
        float4 h4 = *(const float4*)(hp + 4*i4);
        acc += h4.x*wreg[4*i4+0] + h4.y*wreg[4*i4+1]
             + h4.z*wreg[4*i4+2] + h4.w*wreg[4*i4+3];
      }
      part[ke][b][nl] = acc;
    }
    __syncthreads();
    if (tid < 512) {
      int b = tid >> 6, n2 = tid & 63;
      float r = 0.f;
      #pragma unroll
      for (int k16 = 0; k16 < 16; ++k16) r += part[k16][b][n2];
      redR[b][n2] = r;
      float s = r, q = r*r;
      #pragma unroll
      for (int off = 32; off > 0; off >>= 1) { s += __shfl_down(s, off); q += __shfl_down(q, off); }
      if (n2 == 0) {
        astore(Rpart + ((size_t)(rowbase + b)*32 + jb)*2 + 0, s);
        astore(Rpart + ((size_t)(rowbase + b)*32 + jb)*2 + 1, q);
      }
    }
    __syncthreads();   // drains vmcnt => Rpart half0 publishes at MALL
    if (tid == 0) __hip_atomic_store(fA0 + jb*32, t + 1, __ATOMIC_RELAXED, AGENT);

    // ======== GEMV half1 (rows 8-15) + reduce + publish + flagA1 ==========
    #pragma unroll
    for (int b = 0; b < 8; ++b) {
      const float* hp = &hlds[8 + b][ke*32];
      float acc = 0.f;
      #pragma unroll
      for (int i4 = 0; i4 < 8; ++i4) {
        float4 h4 = *(const float4*)(hp + 4*i4);
        acc += h4.x*wreg[4*i4+0] + h4.y*wreg[4*i4+1]
             + h4.z*wreg[4*i4+2] + h4.w*wreg[4*i4+3];
      }
      part[ke][b][nl] = acc;
    }
    __syncthreads();
    if (tid < 512) {
      int b = tid >> 6, n2 = tid & 63;
      float r = 0.f;
      #pragma unroll
      for (int k16 = 0; k16 < 16; ++k16) r += part[k16][b][n2];
      redR[8 + b][n2] = r;
      float s = r, q = r*r;
      #pragma unroll
      for (int off = 32; off > 0; off >>= 1) { s += __shfl_down(s, off); q += __shfl_down(q, off); }
      if (n2 == 0) {
        astore(Rpart + ((size_t)(rowbase + 8 + b)*32 + jb)*2 + 0, s);
        astore(Rpart + ((size_t)(rowbase + 8 + b)*32 + jb)*2 + 1, q);
      }
    }
    __syncthreads();
    if (tid == 0) __hip_atomic_store(fA1 + jb*32, t + 1, __ATOMIC_RELAXED, AGENT);

    // ---- G prefetch for this t (both halves) ----
    float pA0=cgA0,pA1=cgA1,pA2=cgA2,pA3=cgA3;
    float pB0=cgB0,pB1=cgB1,pB2=cgB2,pB3=cgB3;
    if (tid < 128 && !inv_g) {
      const float* ga = Gbuf + (size_t)rowcA * g_row_stride + (size_t)t * g_t_stride;
      const float* gb = Gbuf + (size_t)rowcB * g_row_stride + (size_t)t * g_t_stride;
      pA0 = ga[jc]; pA1 = ga[HH+jc]; pA2 = ga[2*HH+jc]; pA3 = ga[3*HH+jc];
      pB0 = gb[jc]; pB1 = gb[HH+jc]; pB2 = gb[2*HH+jc]; pB3 = gb[3*HH+jc];
    }

    // ======== pollA0 (covered by GEMV1) -> bcR0 -> upd0 -> flagB0 =========
    flagpoll(fA0, t + 1, tid);
    __syncthreads();
    if (tid < 256) {
      float s = aload(Rpart + ((size_t)(rowbase+row8)*32 + j32)*2 + 0);
      float q = aload(Rpart + ((size_t)(rowbase+row8)*32 + j32)*2 + 1);
      #pragma unroll
      for (int off = 16; off > 0; off >>= 1) { s += __shfl_down(s, off, 32); q += __shfl_down(q, off, 32); }
      if (j32 == 0) {
        float mu = s * (1.f/G4);
        bcR[row8][0] = mu;
        bcR[row8][1] = rsqrtf(q*(1.f/G4) - mu*mu + EPSF);
      }
    }
    __syncthreads();
    if (tid < 128) {
      float mu = bcR[bl][0], rstd = bcR[bl][1];
      float gi = pA0 + (redR[bl][jl]    - mu)*rstd*hg0 + hb0;
      float gf = pA1 + (redR[bl][16+jl] - mu)*rstd*hg1 + hb1;
      float go = pA2 + (redR[bl][32+jl] - mu)*rstd*hg2 + hb2;
      float gt = pA3 + (redR[bl][48+jl] - mu)*rstd*hg3 + hb3;
      float iv = fsigmoid(gi), fv = fsigmoid(gf);
      float ov = fsigmoid(go), gv = ftanh(gt);
      cregA = fv*cregA + iv*gv;
      float cs = cregA, cq = cregA*cregA;
      #pragma unroll
      for (int off = 8; off > 0; off >>= 1) { cs += __shfl_down(cs, off, 16); cq += __shfl_down(cq, off, 16); }
      if (jl == 0) {
        astore(Cpart + ((size_t)rowcA*32 + jb)*2 + 0, cs);
        astore(Cpart + ((size_t)rowcA*32 + jb)*2 + 1, cq);
      }
      astore(cbuf + (size_t)rowcA*512 + jc, cregA);
      astore(obuf + (size_t)rowcA*512 + jc, ov);
    }
    __syncthreads();
    if (tid == 0) __hip_atomic_store(fB0 + jb*32, t + 1, __ATOMIC_RELAXED, AGENT);

    // ======== pollA1 (covered by upd0) -> bcR1 -> upd1 -> flagB1 ==========
    flagpoll(fA1, t + 1, tid);
    __syncthreads();
    if (tid < 256) {
      float s = aload(Rpart + ((size_t)(rowbase+8+row8)*32 + j32)*2 + 0);
      float q = aload(Rpart + ((size_t)(rowbase+8+row8)*32 + j32)*2 + 1);
      #pragma unroll
      for (int off = 16; off > 0; off >>= 1) { s += __shfl_down(s, off, 32); q += __shfl_down(q, off, 32); }
      if (j32 == 0) {
        float mu = s * (1.f/G4);
        bcR[8+row8][0] = mu;
        bcR[8+row8][1] = rsqrtf(q*(1.f/G4) - mu*mu + EPSF);
      }
    }
    __syncthreads();
    if (tid < 128) {
      float mu = bcR[8+bl][0], rstd = bcR[8+bl][1];
      float gi = pB0 + (redR[8+bl][jl]    - mu)*rstd*hg0 + hb0;
      float gf = pB1 + (redR[8+bl][16+jl] - mu)*rstd*hg1 + hb1;
      float go = pB2 + (redR[8+bl][32+jl] - mu)*rstd*hg2 + hb2;
      float gt = pB3 + (redR[8+bl][48+jl] - mu)*rstd*hg3 + hb3;
      float iv = fsigmoid(gi), fv = fsigmoid(gf);
      float ov = fsigmoid(go), gv = ftanh(gt);
      cregB = fv*cregB + iv*gv;
      float cs = cregB, cq = cregB*cregB;
      #pragma unroll
      for (int off = 8; off > 0; off >>= 1) { cs += __shfl_down(cs, off, 16); cq += __shfl_down(cq, off, 16); }
      if (jl == 0) {
        astore(Cpart + ((size_t)rowcB*32 + jb)*2 + 0, cs);
        astore(Cpart + ((size_t)rowcB*32 + jb)*2 + 1, cq);
      }
      astore(cbuf + (size_t)rowcB*512 + jc, cregB);
      astore(obuf + (size_t)rowcB*512 + jc, ov);
    }
    __syncthreads();
    if (tid == 0) __hip_atomic_store(fB1 + jb*32, t + 1, __ATOMIC_RELAXED, AGENT);

    // ======== pollB0 (covered by upd1) -> bcC0 -> stage0 ==================
    flagpoll(fB0, t + 1, tid);
    __syncthreads();
    if (tid < 256) {
      float s = aload(Cpart + ((size_t)(rowbase+row8)*32 + j32)*2 + 0);
      float q = aload(Cpart + ((size_t)(rowbase+row8)*32 + j32)*2 + 1);
      #pragma unroll
      for (int off = 16; off > 0; off >>= 1) { s += __shfl_down(s, off, 32); q += __shfl_down(q, off, 32); }
      if (j32 == 0) {
        float mu = s * (1.f/HH);
        bcC[row8][0] = mu;
        bcC[row8][1] = rsqrtf(q*(1.f/HH) - mu*mu + EPSF);
      }
    }
    __syncthreads();
    #pragma unroll
    for (int i = 0; i < 4; ++i) {
      int row = i*2 + srh;
      float c = aload(cbuf + (size_t)(rowbase + row)*512 + scol);
      float o = aload(obuf + (size_t)(rowbase + row)*512 + scol);
      hlds[row][scol] = o * ftanh((c - bcC[row][0]) * bcC[row][1] * ogv + obv);
    }

    // ======== pollB1 (covered by stage0) -> bcC1 -> stage1 ================
    flagpoll(fB1, t + 1, tid);
    __syncthreads();
    if (tid < 256) {
      float s = aload(Cpart + ((size_t)(rowbase+8+row8)*32 + j32)*2 + 0);
      float q = aload(Cpart + ((size_t)(rowbase+8+row8)*32 + j32)*2 + 1);
      #pragma unroll
      for (int off = 16; off > 0; off >>= 1) { s += __shfl_down(s, off, 32); q += __shfl_down(q, off, 32); }
      if (j32 == 0) {
        float mu = s * (1.f/HH);
        bcC[8+row8][0] = mu;
        bcC[8+row8][1] = rsqrtf(q*(1.f/HH) - mu*mu + EPSF);
      }
    }
    __syncthreads();
    #pragma unroll
    for (int i = 0; i < 4; ++i) {
      int row = 8 + i*2 + srh;
      float c = aload(cbuf + (size_t)(rowbase + row)*512 + scol);
      float o = aload(obuf + (size_t)(rowbase + row)*512 + scol);
      hlds[row][scol] = o * ftanh((c - bcC[row][0]) * bcC[row][1] * ogv + obv);
    }
    __syncthreads();   // hlds ready for next step's GEMV
  }

  // ---- final h -> output (jb==0 block of each group writes its 16 rows) ----
  if (jb == 0) {
    #pragma unroll
    for (int i = 0; i < 8; ++i) {
      int row = i*2 + srh;
      fout[(size_t)(bq*16 + row) * 1024 + (size_t)d*512 + scol] = hlds[row][scol];
    }
  }
}

extern "C" void kernel_launch(void* const* d_in, const int* in_sizes, int n_in,
                              void* d_out, int out_size, void* d_ws, size_t ws_size,
                              hipStream_t stream) {
  const float* x        = (const float*)d_in[0];
  const float* w_ih0    = (const float*)d_in[2];
  const float* w_hh0    = (const float*)d_in[3];
  const float* ln_ih0_g = (const float*)d_in[4];
  const float* ln_ih0_b = (const float*)d_in[5];
  const float* ln_hh0_g = (const float*)d_in[6];
  const float* ln_hh0_b = (const float*)d_in[7];
  const float* ln_ho0_g = (const float*)d_in[8];
  const float* ln_ho0_b = (const float*)d_in[9];
  const float* w_ih1    = (const float*)d_in[10];
  const float* w_hh1    = (const float*)d_in[11];
  const float* ln_ih1_g = (const float*)d_in[12];
  const float* ln_ih1_b = (const float*)d_in[13];
  const float* ln_hh1_g = (const float*)d_in[14];
  const float* ln_hh1_b = (const float*)d_in[15];
  const float* ln_ho1_g = (const float*)d_in[16];
  const float* ln_ho1_b = (const float*)d_in[17];
  float* out = (float*)d_out;

  // ws (floats): G0 12.58M | g1pre 262K | xcb 64K | Rpart 8K |
  //   [zero region: Cpart 8K | cbuf 64K | obuf 64K | ints 65600] ~= 52.6 MB
  float* G0    = (float*)d_ws;
  float* g1pre = G0 + (size_t)2*BB*SS*G4;
  float* xcb   = g1pre + (size_t)2*BB*G4;
  float* Rpart = xcb + (size_t)BB*1024;
  float* Cpart = Rpart + (size_t)128*32*2;
  float* cbuf  = Cpart + (size_t)128*32*2;
  float* obuf  = cbuf + (size_t)128*512;
  int*   ints  = (int*)(obuf + (size_t)128*512);
  int*   fA_l0   = ints;                 // 2 halves x 8 groups x 1024
  int*   fB_l0   = ints + 16384;
  int*   fA_l1   = ints + 32768;
  int*   fB_l1   = ints + 49152;
  int*   cnt_pre = ints + 65536;         // 64 ints

  // zero Cpart + cbuf + obuf + all flags/counters (contiguous)
  hipMemsetAsync(Cpart, 0, ((size_t)128*32*2 + 2*(size_t)128*512)*sizeof(float)
                           + 65600*sizeof(int), stream);

  // phase A: G0 = LN(x @ w_ih0^T), time-reversal baked in for d=1
  hipLaunchKernelGGL(gemm_ih0, dim3(G4/64, (2*BB*SS)/64), dim3(256), 0, stream,
      x, w_ih0, G0);
  hipLaunchKernelGGL(ln_rows, dim3(2*BB*SS), dim3(256), 0, stream,
      G0, ln_ih0_g, ln_ih0_b, BB*SS);

  // layer 0 scan -> xcb
  hipLaunchKernelGGL(persistP, dim3(256), dim3(1024), 0, stream,
      w_hh0, G0, (long)SS*G4, (long)G4,
      ln_hh0_g, ln_hh0_b, ln_ho0_g, ln_ho0_b,
      cbuf, obuf, Rpart, Cpart, fA_l0, fB_l0, xcb, SS,
      0, (const float*)nullptr, (const float*)nullptr, (float*)nullptr,
      (const float*)nullptr, (const float*)nullptr, (int*)nullptr);

  // layer 1: projection + LN in preamble, then scan (t-stride 0) -> out
  hipLaunchKernelGGL(persistP, dim3(256), dim3(1024), 0, stream,
      w_hh1, g1pre, (long)G4, 0L,
      ln_hh1_g, ln_hh1_b, ln_ho1_g, ln_ho1_b,
      cbuf, obuf, Rpart, Cpart, fA_l1, fB_l1, out, SS,
      1, w_ih1, xcb, g1pre, ln_ih1_g, ln_ih1_b, cnt_pre);
}